// Round 20
// baseline (155.798 us; speedup 1.0000x reference)
//
#include <hip/hip_runtime.h>
#include <hip/hip_bf16.h>

// GraphSAGE fused kernels for MI355X (gfx950).
// N=768, NODE_IN=64, EDGE_IN=32, H=128, ROUNDS=2.
//
// Round 20: k_bfr = eproj build FUSED with round-1 aggregation. Block =
// (16-j stripe, 48-i segment); per i: 16x128 eproj tile via R19's verified
// double-swapped GEMMs, round-1 accumulate straight from fp32 MFMA regs
// (acc += relu(D + sp[i][k]) * adj[i][j]), eproj written via o_lds-staged
// coalesced stores. Kills round-1's separate 151MB k_round pass (~22us) and
// k_build's 32-row lockstep. Round 2 = verified streaming k_round. LDS
// 16.5KB, 1 barrier/i.

typedef __bf16 bf16x8 __attribute__((ext_vector_type(8)));
typedef float f32x4 __attribute__((ext_vector_type(4)));

#define NN 768

static __device__ __forceinline__ unsigned short to_bf16u(float x) {
    return __builtin_bit_cast(unsigned short, (__bf16)x);
}

// ---------------------------------------------------------------- fused prep
// blocks 0..79   : weight transposes We->WeT, Wa[H:]->Wa2T (bf16 k-minor)
// blocks 80..463 : h0 = relu(nf@Wn+bn) and sp = h0@Wa[:H]+ba
// blocks 464..475: invdeg[j] = 1/max(sum_i adj[i][j], 1)
__global__ __launch_bounds__(256) void k_prep(
                       const float* __restrict__ adj,
                       const float* __restrict__ We, const float* __restrict__ Wa,
                       unsigned short* __restrict__ WeT, unsigned short* __restrict__ Wa2T,
                       const float* __restrict__ nf, const float* __restrict__ Wn,
                       const float* __restrict__ bn, const float* __restrict__ ba,
                       float* __restrict__ h, float* __restrict__ sp,
                       float* __restrict__ invdeg) {
    const int b = blockIdx.x, tid = threadIdx.x;
    if (b < 80) {
        int g = b * 256 + tid;
        if (g < 128 * 32) {
            int c = g >> 5, f = g & 31;
            WeT[g] = to_bf16u(We[f * 128 + c]);
        } else {
            int g2 = g - 128 * 32;
            int c = g2 >> 7, k = g2 & 127;
            Wa2T[g2] = to_bf16u(Wa[(128 + k) * 128 + c]);
        }
    } else if (b < 464) {
        __shared__ float nf_l[2][64];
        __shared__ float h_l[2][128];
        int row = tid >> 7, t = tid & 127;
        int i = (b - 80) * 2 + row;
        if (t < 64) nf_l[row][t] = nf[i * 64 + t];
        __syncthreads();
        float acc = bn[t];
#pragma unroll 8
        for (int f = 0; f < 64; ++f) acc += nf_l[row][f] * Wn[f * 128 + t];
        acc = fmaxf(acc, 0.f);
        h[i * 128 + t] = acc;
        h_l[row][t] = acc;
        __syncthreads();
        float spv = ba[t];
#pragma unroll 8
        for (int f = 0; f < 128; ++f) spv += h_l[row][f] * Wa[f * 128 + t];
        sp[i * 128 + t] = spv;
    } else {
        __shared__ float dsum[4][64];
        int d = b - 464;
        int q = tid >> 6, jj = tid & 63;
        int j = d * 64 + jj;
        float s = 0.f;
        for (int i = q * 192; i < q * 192 + 192; ++i)
            s += adj[(size_t)i * NN + j];
        dsum[q][jj] = s;
        __syncthreads();
        if (tid < 64) {
            float tot = dsum[0][tid] + dsum[1][tid] + dsum[2][tid] + dsum[3][tid];
            invdeg[d * 64 + tid] = 1.0f / fmaxf(tot, 1.0f);
        }
    }
}

// ---------------------------------------------------------------- build + round-1 fused
// Block = (jt, iseg): j0 = 16*jt, senders i in [48*iseg, 48*iseg+48).
// 8 waves; wave wv owns 16 H/K cols [16wv, 16wv+16). Per i: 16x128 tile.
// Lane (lg,lr) holds j = j0+lr, 4 consecutive cols 16wv+4lg+{0..3}.
__global__ __launch_bounds__(512) void k_bfr(
    const float* __restrict__ ef, const float* __restrict__ adj,
    const float* __restrict__ sp, const unsigned short* __restrict__ WeT,
    const unsigned short* __restrict__ Wa2T, const float* __restrict__ be,
    unsigned short* __restrict__ eproj, float* __restrict__ aggp) {
    __shared__ __align__(16) unsigned short e_lds[2][16 * 128];  // 8KB dbuf, [j][H]
    __shared__ __align__(16) unsigned short o_lds[2][16 * 128];  // 8KB dbuf, [j][K]
    const int tid  = threadIdx.x;
    const int lane = tid & 63;
    const int wv   = tid >> 6;
    const int lg   = lane >> 4;
    const int lr   = lane & 15;
    const int jt   = blockIdx.x >> 4;
    const int iseg = blockIdx.x & 15;
    const int j0   = jt * 16;
    const int ibase = iseg * 48;

    // weight A-operand frags + be C-init (R19-verified formulas, 16-col tiles)
    const int col = 16 * wv + lr;
    bf16x8 bwe = *reinterpret_cast<const bf16x8*>(WeT + col * 32 + 8 * lg);
    f32x4  bev = *reinterpret_cast<const f32x4*>(be + 16 * wv + 4 * lg);
    bf16x8 bwa[4];
#pragma unroll
    for (int s = 0; s < 4; ++s)
        bwa[s] = *reinterpret_cast<const bf16x8*>(Wa2T + col * 128 + 32 * s + 8 * lg);

    // ef B-operand frag for sender ii: lane holds column j0+lr, feats 8lg..+8
    auto load_a = [&](int ii, bf16x8& x) {
        const float* p = ef + ((size_t)ii * NN + j0 + lr) * 32 + 8 * lg;
        float4 f0 = *reinterpret_cast<const float4*>(p);
        float4 f1 = *reinterpret_cast<const float4*>(p + 4);
        x[0] = (__bf16)f0.x; x[1] = (__bf16)f0.y; x[2] = (__bf16)f0.z; x[3] = (__bf16)f0.w;
        x[4] = (__bf16)f1.x; x[5] = (__bf16)f1.y; x[6] = (__bf16)f1.z; x[7] = (__bf16)f1.w;
    };
    // GEMM1 swapped: D = We^T @ EF^T + be -> lane: j=j0+lr, H=16wv+4lg+r
    auto gemm1 = [&](bf16x8 aef, int buf) {
        f32x4 D = __builtin_amdgcn_mfma_f32_16x16x32_bf16(bwe, aef, bev, 0, 0, 0);
        ushort4 pk;
        pk.x = to_bf16u(fmaxf(D[0], 0.f));
        pk.y = to_bf16u(fmaxf(D[1], 0.f));
        pk.z = to_bf16u(fmaxf(D[2], 0.f));
        pk.w = to_bf16u(fmaxf(D[3], 0.f));
        int idx = (lr * 128 + 16 * wv + 4 * lg) ^ ((lr & 7) << 3);
        *reinterpret_cast<ushort4*>(&e_lds[buf][idx]) = pk;
    };

    f32x4 acc;
    acc[0] = 0.f; acc[1] = 0.f; acc[2] = 0.f; acc[3] = 0.f;

    bf16x8 cA, pA;
    load_a(ibase, cA);
    gemm1(cA, 0);
    load_a(ibase + 1, cA);
    __syncthreads();   // E[0] ready

    for (int m = 0; m < 48; ++m) {
        const int b = m & 1;
        const int ii = ibase + m;
        if (m + 2 < 48) load_a(ibase + m + 2, pA);
        if (m + 1 < 48) gemm1(cA, b ^ 1);

        // GEMM2 swapped: D = Wa2^T @ E^T -> lane: j=j0+lr, K=16wv+4lg+r
        bf16x8 eb[4];
#pragma unroll
        for (int s = 0; s < 4; ++s) {
            int idx = (lr * 128 + 32 * s + 8 * lg) ^ ((lr & 7) << 3);
            eb[s] = *reinterpret_cast<const bf16x8*>(&e_lds[b][idx]);
        }
        f32x4 D;
        D[0] = 0.f; D[1] = 0.f; D[2] = 0.f; D[3] = 0.f;
#pragma unroll
        for (int s = 0; s < 4; ++s)
            D = __builtin_amdgcn_mfma_f32_16x16x32_bf16(bwa[s], eb[s], D, 0, 0, 0);

        // round-1 accumulate from fp32 regs
        f32x4 spv = *reinterpret_cast<const f32x4*>(sp + (size_t)ii * 128 + 16 * wv + 4 * lg);
        float av = adj[(size_t)ii * NN + j0 + lr];
#pragma unroll
        for (int r = 0; r < 4; ++r)
            acc[r] += fmaxf(D[r] + spv[r], 0.f) * av;

        // pack eproj tile to o_lds
        ushort4 pk;
        pk.x = to_bf16u(D[0]); pk.y = to_bf16u(D[1]);
        pk.z = to_bf16u(D[2]); pk.w = to_bf16u(D[3]);
        int oidx = (lr * 128 + 16 * wv + 4 * lg) ^ ((lr & 7) << 3);
        *reinterpret_cast<ushort4*>(&o_lds[b][oidx]) = pk;
        __syncthreads();   // o_lds[b] complete; e_lds[b^1] complete

        // coalesced eproj store: 256 threads x 16B = 16 rows x 256B
        if (tid < 256) {
            const int srow = tid >> 4, a = tid & 15;
            int idx = srow * 128 + 8 * (a ^ (srow & 7));
            f32x4 v = *reinterpret_cast<const f32x4*>(&o_lds[b][idx]);
            *reinterpret_cast<f32x4*>(eproj + ((size_t)ii * NN + j0 + srow) * 128 + 8 * a) = v;
        }

        if (m + 2 < 48) cA = pA;
    }

    // write round-1 partial: aggp[j][iseg][k]
    *reinterpret_cast<f32x4*>(
        aggp + ((size_t)(j0 + lr) * 16 + iseg) * 128 + 16 * wv + 4 * lg) = acc;
}

// ---------------------------------------------------------------- streaming round (round 2)
// Block b: jt = b>>4 (16 receivers j0=jt*16), seg = b&15 (48 senders).
// acc[j][k] += relu(sp[i][k] + eproj[i*768+j][k]) * adj[i][j].
__global__ __launch_bounds__(256) void k_round(
    const unsigned short* __restrict__ eproj, const float* __restrict__ adj,
    const float* __restrict__ sp, float* __restrict__ aggp) {
    const int tid = threadIdx.x;
    const int jt  = blockIdx.x >> 4;
    const int seg = blockIdx.x & 15;
    const int j0  = jt * 16;
    const int i0  = seg * 48;
    const int jj  = tid >> 4;
    const int kb  = (tid & 15) * 8;

    const size_t estep = (size_t)NN * 128;
    const unsigned short* ep = eproj + ((size_t)i0 * NN + j0 + jj) * 128 + kb;
    const float* ap = adj + (size_t)i0 * NN + j0 + jj;
    const float* spp = sp + (size_t)i0 * 128 + kb;

    float acc[8] = {0.f, 0.f, 0.f, 0.f, 0.f, 0.f, 0.f, 0.f};

    bf16x8 v = *reinterpret_cast<const bf16x8*>(ep);
    float av = *ap;
    float4 s0 = *reinterpret_cast<const float4*>(spp);
    float4 s1 = *reinterpret_cast<const float4*>(spp + 4);

    for (int m = 0; m < 48; ++m) {
        bf16x8 vn = v; float avn = av; float4 s0n = s0, s1n = s1;
        if (m < 47) {
            vn = *reinterpret_cast<const bf16x8*>(ep + estep);
            avn = ap[NN];
            s0n = *reinterpret_cast<const float4*>(spp + 128);
            s1n = *reinterpret_cast<const float4*>(spp + 132);
        }
        acc[0] += fmaxf(s0.x + (float)v[0], 0.f) * av;
        acc[1] += fmaxf(s0.y + (float)v[1], 0.f) * av;
        acc[2] += fmaxf(s0.z + (float)v[2], 0.f) * av;
        acc[3] += fmaxf(s0.w + (float)v[3], 0.f) * av;
        acc[4] += fmaxf(s1.x + (float)v[4], 0.f) * av;
        acc[5] += fmaxf(s1.y + (float)v[5], 0.f) * av;
        acc[6] += fmaxf(s1.z + (float)v[6], 0.f) * av;
        acc[7] += fmaxf(s1.w + (float)v[7], 0.f) * av;
        ep += estep; ap += NN; spp += 128;
        v = vn; av = avn; s0 = s0n; s1 = s1n;
    }

    float* dst = aggp + ((size_t)(j0 + jj) * 16 + seg) * 128 + kb;
    float4 o0, o1;
    o0.x = acc[0]; o0.y = acc[1]; o0.z = acc[2]; o0.w = acc[3];
    o1.x = acc[4]; o1.y = acc[5]; o1.z = acc[6]; o1.w = acc[7];
    *reinterpret_cast<float4*>(dst) = o0;
    *reinterpret_cast<float4*>(dst + 4) = o1;
}

// ---------------------------------------------------------------- update (reduce partials + GEMM)
template <int LAST>
__global__ __launch_bounds__(256) void k_upd(
                      const float* __restrict__ h_in, const float* __restrict__ aggp,
                      const float* __restrict__ invdeg,
                      const float* __restrict__ Wu, const float* __restrict__ bu,
                      const float* __restrict__ Wa, const float* __restrict__ ba,
                      float* __restrict__ h_out, float* __restrict__ sp,
                      float* __restrict__ out) {
    __shared__ float buf[2][256];
    __shared__ float hn[2][128];
    const int tid = threadIdx.x;
    const int row = tid >> 7, t = tid & 127;
    const int j = blockIdx.x * 2 + row;
    float s = 0.f;
#pragma unroll
    for (int seg = 0; seg < 16; ++seg)
        s += aggp[((size_t)j * 16 + seg) * 128 + t];
    buf[row][t] = h_in[j * 128 + t];
    buf[row][128 + t] = s * invdeg[j];
    __syncthreads();
    float acc = bu[t];
#pragma unroll 8
    for (int f = 0; f < 256; ++f) acc += buf[row][f] * Wu[f * 128 + t];
    acc = fmaxf(acc, 0.f);
    if (LAST) {
        out[j * 128 + t] = acc;
    } else {
        h_out[j * 128 + t] = acc;
        hn[row][t] = acc;
        __syncthreads();
        float spv = ba[t];
#pragma unroll 8
        for (int f = 0; f < 128; ++f) spv += hn[row][f] * Wa[f * 128 + t];
        sp[j * 128 + t] = spv;
    }
}

// ---------------------------------------------------------------- graph embedding
__global__ __launch_bounds__(64) void k_gemb(const float* __restrict__ out_h, float* __restrict__ out) {
    int c = blockIdx.x, l = threadIdx.x;
    float acc = 0.f;
    for (int i = l; i < NN; i += 64) acc += out_h[(size_t)i * 128 + c];
#pragma unroll
    for (int off = 32; off; off >>= 1) acc += __shfl_down(acc, off);
    if (l == 0) out[NN * 128 + c] = acc * (1.0f / 768.0f);
}

extern "C" void kernel_launch(void* const* d_in, const int* in_sizes, int n_in,
                              void* d_out, int out_size, void* d_ws, size_t ws_size,
                              hipStream_t stream) {
    const float* nf  = (const float*)d_in[0];
    const float* ef  = (const float*)d_in[1];
    const float* adj = (const float*)d_in[2];
    const float* Wn  = (const float*)d_in[3];
    const float* bn  = (const float*)d_in[4];
    const float* We  = (const float*)d_in[5];
    const float* be  = (const float*)d_in[6];
    const float* Wa  = (const float*)d_in[7];
    const float* ba  = (const float*)d_in[8];
    const float* Wu  = (const float*)d_in[9];
    const float* bu  = (const float*)d_in[10];
    float* out = (float*)d_out;

    // ws layout (floats): h | sp | invdeg | aggp | WeT(us) | Wa2T(us) | eproj(us)
    float* h_buf  = (float*)d_ws;
    float* sp     = h_buf + NN * 128;
    float* invdeg = sp + NN * 128;
    float* aggp   = invdeg + NN;
    unsigned short* WeT   = (unsigned short*)(aggp + (size_t)NN * 16 * 128);
    unsigned short* Wa2T  = WeT + 128 * 32;
    unsigned short* eproj = Wa2T + 128 * 128;

    k_prep<<<476, 256, 0, stream>>>(adj, We, Wa, WeT, Wa2T, nf, Wn, bn, ba,
                                    h_buf, sp, invdeg);

    // round 1: build eproj + aggregate in one pass
    k_bfr<<<48 * 16, 512, 0, stream>>>(ef, adj, sp, WeT, Wa2T, be, eproj, aggp);
    k_upd<0><<<NN / 2, 256, 0, stream>>>(h_buf, aggp, invdeg, Wu, bu, Wa, ba, h_buf, sp, out);

    // round 2: stream materialized eproj
    k_round<<<48 * 16, 256, 0, stream>>>(eproj, adj, sp, aggp);
    k_upd<1><<<NN / 2, 256, 0, stream>>>(h_buf, aggp, invdeg, Wu, bu, Wa, ba, h_buf, sp, out);

    k_gemb<<<128, 64, 0, stream>>>(out, out);
}